// Round 2
// baseline (559.971 us; speedup 1.0000x reference)
//
#include <hip/hip_runtime.h>
#include <cstdint>

// ============================================================================
// Gtu: u=silu(x@Wu+bu); v=silu(x@Wv+bv); per-channel causal conv of v with
// RPE-generated decayed kernel (rfft4096 via packed cfft2048); out=(u*conv)@Wo+bo
// Workspace budget ~147MB (round-1 was 259MB -> likely ws overflow -> abort).
// ============================================================================

typedef unsigned short ushort_t;                                    // bf16 bits
typedef __attribute__((ext_vector_type(8))) short short8;           // MFMA A/B frag
typedef __attribute__((ext_vector_type(4))) float f32x4;            // MFMA acc

#define AS1 __attribute__((address_space(1)))
#define AS3 __attribute__((address_space(3)))

__device__ __forceinline__ float bf2f(ushort_t b) {
  union { unsigned u; float f; } x; x.u = ((unsigned)b) << 16; return x.f;
}
__device__ __forceinline__ ushort_t f2bf(float f) {
  union { float f; unsigned u; } x; x.f = f;
  unsigned r = x.u + 0x7fffu + ((x.u >> 16) & 1u);   // RNE
  return (ushort_t)(r >> 16);
}

// CK-style addrspace cast (flat LDS addr low 32 bits == LDS offset on gfx9)
__device__ __forceinline__ void gload_lds16(const void* g, void* l) {
  auto gp = reinterpret_cast<const AS1 unsigned*>(reinterpret_cast<uintptr_t>(g));
  auto lp = reinterpret_cast<AS3 unsigned*>(reinterpret_cast<uintptr_t>(l));
  __builtin_amdgcn_global_load_lds(gp, lp, 16, 0, 0);
}

// ---------------------------------------------------------------------------
// bf16 GEMM: C = A[M][K] @ Bt[N][K]^T (+bias). 128x128x64 tiles, 4 waves.
// MODE 0: fp32 store to Cout[M][N].
// MODE 2: val*gamma^row, fp32 store transposed Cout[col*M+row]  (RPE kernel).
// MODE 3: silu; col<1536 -> bf16 Cout[row*1536+col] (u);
//               col>=1536 -> bf16 Cout2[(col-1536)*16384+row] (v transposed).
// ---------------------------------------------------------------------------
template<int MODE>
__launch_bounds__(256, 2)
__global__ void gemm_bt(const ushort_t* __restrict__ A, const ushort_t* __restrict__ Bt,
                        const float* __restrict__ bias, void* __restrict__ Cout,
                        void* __restrict__ Cout2, int M, int N, int K, float lng)
{
  __shared__ ushort_t As[128 * 64];
  __shared__ ushort_t Bs[128 * 64];
  const int tid  = threadIdx.x;
  const int wave = tid >> 6, lane = tid & 63;
  const int nb = N >> 7;
  const int bm = (int)blockIdx.x / nb, bn = (int)blockIdx.x % nb;
  const int m0 = bm << 7, n0 = bn << 7;
  const int lrow = lane & 15, quad = lane >> 4;
  const int wm = (wave >> 1) << 6, wn = (wave & 1) << 6;
  const int srow = lane >> 3;            // 0..7 (row within 8-row chunk)
  const int scol = (lane & 7) << 3;      // bf16 col (8-elem granules)

  f32x4 acc[4][4] = {};

  for (int kt = 0; kt < K; kt += 64) {
    __syncthreads();
#pragma unroll
    for (int i = 0; i < 4; ++i) {
      const int ci  = i * 4 + wave;      // chunk 0..15, wave-uniform
      const int row = ci * 8 + srow;
      gload_lds16(A  + (long)(m0 + row) * K + kt + scol, (void*)&As[ci * 512]);
      gload_lds16(Bt + (long)(n0 + row) * K + kt + scol, (void*)&Bs[ci * 512]);
    }
    __syncthreads();   // compiler drains vmcnt before s_barrier
#pragma unroll
    for (int s = 0; s < 2; ++s) {
      short8 afr[4], bfr[4];
#pragma unroll
      for (int i = 0; i < 4; ++i)
        afr[i] = *(const short8*)&As[(wm + i * 16 + lrow) * 64 + s * 32 + quad * 8];
#pragma unroll
      for (int j = 0; j < 4; ++j)
        bfr[j] = *(const short8*)&Bs[(wn + j * 16 + lrow) * 64 + s * 32 + quad * 8];
#pragma unroll
      for (int i = 0; i < 4; ++i)
#pragma unroll
        for (int j = 0; j < 4; ++j)
          acc[i][j] = __builtin_amdgcn_mfma_f32_16x16x32_bf16(afr[i], bfr[j], acc[i][j], 0, 0, 0);
    }
  }

#pragma unroll
  for (int i = 0; i < 4; ++i) {
    const int rowb = m0 + wm + i * 16 + quad * 4;
#pragma unroll
    for (int j = 0; j < 4; ++j) {
      const int col = n0 + wn + j * 16 + lrow;
      const float bv = bias[col];
      if (MODE == 0) {
#pragma unroll
        for (int r = 0; r < 4; ++r)
          ((float*)Cout)[(long)(rowb + r) * N + col] = acc[i][j][r] + bv;
      } else if (MODE == 2) {
#pragma unroll
        for (int r = 0; r < 4; ++r) {
          const int row = rowb + r;
          float dec = __expf(lng * (float)row);           // gamma^row
          ((float*)Cout)[(long)col * M + row] = (acc[i][j][r] + bv) * dec;
        }
      } else {  // MODE 3
        if (col < 1536) {
#pragma unroll
          for (int r = 0; r < 4; ++r) {
            float val = acc[i][j][r] + bv;
            float sv = val / (1.f + __expf(-val));
            ((ushort_t*)Cout)[(long)(rowb + r) * 1536 + col] = f2bf(sv);
          }
        } else {
          union { ushort_t h[4]; uint2 u2; } pk;
#pragma unroll
          for (int r = 0; r < 4; ++r) {
            float val = acc[i][j][r] + bv;
            float sv = val / (1.f + __expf(-val));
            pk.h[r] = f2bf(sv);
          }
          *(uint2*)((ushort_t*)Cout2 + (long)(col - 1536) * 16384 + rowb) = pk.u2;
        }
      }
    }
  }
}

// ---------------------------------------------------------------------------
// Weight transpose+convert: dst[n][k] (bf16) = src[k][n] (fp32)
// ---------------------------------------------------------------------------
__launch_bounds__(256)
__global__ void wtrans(const float* __restrict__ src, ushort_t* __restrict__ dst, int K, int N)
{
  __shared__ float tile[32][33];
  const int nbx = N >> 5;
  const int bx = (int)blockIdx.x % nbx, by = (int)blockIdx.x / nbx;
  const int n0 = bx << 5, k0 = by << 5;
  const int tx = threadIdx.x & 31, ty = threadIdx.x >> 5;   // ty 0..7
  for (int yy = ty; yy < 32; yy += 8)
    tile[yy][tx] = src[(long)(k0 + yy) * N + n0 + tx];
  __syncthreads();
  for (int yy = ty; yy < 32; yy += 8)
    dst[(long)(n0 + yy) * K + k0 + tx] = f2bf(tile[tx][yy]);
}

__launch_bounds__(256)
__global__ void concat_bias(const float* __restrict__ a, const float* __restrict__ b,
                            float* __restrict__ dst)
{
  int i = blockIdx.x * 256 + threadIdx.x;
  if (i < 1536) { dst[i] = a[i]; dst[1536 + i] = b[i]; }
}

__launch_bounds__(256)
__global__ void cvt_bf16(const float* __restrict__ src, ushort_t* __restrict__ dst)
{
  long i = (long)(blockIdx.x * 256 + threadIdx.x) * 4;
  float4 f = *(const float4*)(src + i);
  unsigned lo = (unsigned)f2bf(f.x) | ((unsigned)f2bf(f.y) << 16);
  unsigned hi = (unsigned)f2bf(f.z) | ((unsigned)f2bf(f.w) << 16);
  *(uint2*)(dst + i) = make_uint2(lo, hi);
}

// ---------------------------------------------------------------------------
// RPE rows: srms -> relu -> bf16 (one 256-thr block per row of 512)
// ---------------------------------------------------------------------------
__device__ __forceinline__ void srms_relu_store(float v0, float v1, ushort_t* out,
                                                long rowbase, int tid)
{
  float ss = v0 * v0 + v1 * v1;
#pragma unroll
  for (int off = 32; off; off >>= 1) ss += __shfl_down(ss, off);
  __shared__ float ps[4];
  const int wave = tid >> 6, lane = tid & 63;
  if (lane == 0) ps[wave] = ss;
  __syncthreads();
  float tot = ps[0] + ps[1] + ps[2] + ps[3];
  float sc = 1.f / (sqrtf(tot * (1.f / 512.f)) + 1e-6f);
  out[rowbase + tid]       = f2bf(fmaxf(v0 * sc, 0.f));
  out[rowbase + tid + 256] = f2bf(fmaxf(v1 * sc, 0.f));
}

__launch_bounds__(256)
__global__ void rpe_h0(const float* __restrict__ Win, const float* __restrict__ bin,
                       ushort_t* __restrict__ out)
{
  const int n = blockIdx.x, tid = threadIdx.x;
  const float fn = (float)n;
  float v0 = fn * Win[tid] + bin[tid];
  float v1 = fn * Win[tid + 256] + bin[tid + 256];
  srms_relu_store(v0, v1, out, (long)n * 512, tid);
}

__launch_bounds__(256)
__global__ void rpe_norm(const float* __restrict__ h, ushort_t* __restrict__ out)
{
  const int n = blockIdx.x, tid = threadIdx.x;
  float v0 = h[(long)n * 512 + tid];
  float v1 = h[(long)n * 512 + tid + 256];
  srms_relu_store(v0, v1, out, (long)n * 512, tid);
}

// ---------------------------------------------------------------------------
// In-LDS 2048-pt complex FFT (Stockham: radix-2 then 5x radix-4).
// Input arg0, scratch arg1, result lands back in arg0. tw[j]=cis(-2*pi*j/2048).
// ---------------------------------------------------------------------------
__device__ __forceinline__ float2 cmulf(float2 a, float2 b) {
  return make_float2(a.x * b.x - a.y * b.y, a.x * b.y + a.y * b.x);
}

__device__ void fft2048_lds(float2* bx, float2* by, const float2* tw, int tid)
{
  for (int i = tid; i < 1024; i += 256) {      // radix-2, p=1
    float2 a = bx[i], b = bx[i + 1024];
    by[2 * i]     = make_float2(a.x + b.x, a.y + b.y);
    by[2 * i + 1] = make_float2(a.x - b.x, a.y - b.y);
  }
  __syncthreads();
  float2* src = by; float2* dst = bx;
  for (int ps = 0; ps < 5; ++ps) {             // radix-4, p = 2,8,32,128,512
    const int p = 2 << (2 * ps);
    const int ts = 512 / p;
    for (int i = tid; i < 512; i += 256) {
      const int k = i & (p - 1);
      float2 u0 = src[i], u1 = src[i + 512], u2 = src[i + 1024], u3 = src[i + 1536];
      const int tb = k * ts;
      float2 w1 = tw[tb], w2 = tw[2 * tb], w3 = tw[3 * tb];
      u1 = cmulf(u1, w1); u2 = cmulf(u2, w2); u3 = cmulf(u3, w3);
      float2 v0 = make_float2(u0.x + u2.x, u0.y + u2.y);
      float2 v2 = make_float2(u0.x - u2.x, u0.y - u2.y);
      float2 v1 = make_float2(u1.x + u3.x, u1.y + u3.y);
      float2 v3 = make_float2(u1.y - u3.y, u3.x - u1.x);   // (u1-u3)*(-i)
      const int j = ((i - k) << 2) + k;
      dst[j]         = make_float2(v0.x + v1.x, v0.y + v1.y);
      dst[j + p]     = make_float2(v2.x + v3.x, v2.y + v3.y);
      dst[j + 2 * p] = make_float2(v0.x - v1.x, v0.y - v1.y);
      dst[j + 3 * p] = make_float2(v2.x - v3.x, v2.y - v3.y);
    }
    __syncthreads();
    float2* t = src; src = dst; dst = t;
  }
}

__device__ __forceinline__ void build_tw(float2* tw, int tid)
{
  for (int j = tid; j < 2048; j += 256) {
    float s, c; __sincosf((float)j * (6.283185307179586f / 2048.f), &s, &c);
    tw[j] = make_float2(c, -s);
  }
}

// Kernel spectrum: af[c][k] = rfft_4096(kern[c][0:2048] zero-padded), k=0..2048
__launch_bounds__(256)
__global__ void fft_kernel_spec(const float* __restrict__ kern, float2* __restrict__ af)
{
  __shared__ float2 bx[2048], by[2048], tw[2048];
  const int tid = threadIdx.x, c = blockIdx.x;
  build_tw(tw, tid);
  const float* kc = kern + (long)c * 2048;
  for (int j = tid; j < 1024; j += 256) bx[j] = *(const float2*)(kc + 2 * j);
  for (int j = tid + 1024; j < 2048; j += 256) bx[j] = make_float2(0.f, 0.f);
  __syncthreads();
  fft2048_lds(bx, by, tw, tid);
  float2* afc = af + (long)c * 2052;
  for (int k = tid; k <= 1024; k += 256) {
    float2 Zk = bx[k], Zn = bx[(2048 - k) & 2047];
    float2 E = make_float2(0.5f * (Zk.x + Zn.x), 0.5f * (Zk.y - Zn.y));
    float2 O = make_float2(0.5f * (Zk.y + Zn.y), 0.5f * (Zn.x - Zk.x));
    float s, co; __sincosf((float)k * (3.14159265358979f / 2048.f), &s, &co);
    float2 W = make_float2(co, -s);
    float2 WO = cmulf(W, O);
    afc[k] = make_float2(E.x + WO.x, E.y + WO.y);
    if (k != 0 && k != 1024)
      afc[2048 - k] = make_float2(E.x - WO.x, -(E.y - WO.y));
    if (k == 0)
      afc[2048] = make_float2(E.x - WO.x, -(E.y - WO.y));
  }
}

// Conv (IN PLACE on vt): y = irfft4096(rfft4096(v)*af)[0:2048], block=(c,b) seq
__launch_bounds__(256)
__global__ void fft_conv(ushort_t* __restrict__ vt, const float2* __restrict__ af)
{
  __shared__ float2 bx[2048], by[2048], tw[2048];
  const int tid = threadIdx.x;
  const int c = (int)blockIdx.x >> 3;
  build_tw(tw, tid);
  ushort_t* vs = vt + (long)blockIdx.x * 2048;
  for (int j = tid; j < 1024; j += 256) {
    unsigned pv = *(const unsigned*)(vs + 2 * j);
    bx[j] = make_float2(bf2f((ushort_t)(pv & 0xffffu)), bf2f((ushort_t)(pv >> 16)));
  }
  for (int j = tid + 1024; j < 2048; j += 256) bx[j] = make_float2(0.f, 0.f);
  __syncthreads();
  fft2048_lds(bx, by, tw, tid);                 // bx = Z (packed fwd FFT)
  const float2* afc = af + (long)c * 2052;
  for (int k = tid; k <= 1024; k += 256) {
    float2 Zk = bx[k], Zn = bx[(2048 - k) & 2047];
    float2 E = make_float2(0.5f * (Zk.x + Zn.x), 0.5f * (Zk.y - Zn.y));
    float2 O = make_float2(0.5f * (Zk.y + Zn.y), 0.5f * (Zn.x - Zk.x));
    float s, co; __sincosf((float)k * (3.14159265358979f / 2048.f), &s, &co);
    float2 W = make_float2(co, -s);
    float2 WO = cmulf(W, O);
    float2 Xk = make_float2(E.x + WO.x, E.y + WO.y);          // rfft(v)[k]
    float2 Xn = make_float2(E.x - WO.x, -(E.y - WO.y));       // rfft(v)[2048-k]
    float2 Pk = cmulf(Xk, afc[k]);
    float2 Pn = cmulf(Xn, afc[2048 - k]);
    // E2=(Pk+conj(Pn))/2, G=(Pk-conj(Pn))/2, Fo=conj(W)*G, W2=E2+i*Fo
    float2 E2 = make_float2(0.5f * (Pk.x + Pn.x), 0.5f * (Pk.y - Pn.y));
    float2 G  = make_float2(0.5f * (Pk.x - Pn.x), 0.5f * (Pk.y + Pn.y));
    float2 cW = make_float2(W.x, -W.y);
    float2 Fo = cmulf(cW, G);
    by[k] = make_float2(E2.x - Fo.y, -(E2.y + Fo.x));          // conj(W2[k])
    if (k != 0 && k != 1024)
      by[2048 - k] = make_float2(E2.x + Fo.y, E2.y - Fo.x);    // conj(W2[2048-k])
  }
  __syncthreads();
  fft2048_lds(by, bx, tw, tid);                 // by = FFT(conj(W2))
  const float inv = 1.f / 2048.f;
  for (int j = tid; j < 1024; j += 256) {       // z[j]=conj(by[j])/2048
    float2 r = by[j];
    unsigned ov = (unsigned)f2bf(r.x * inv) | ((unsigned)f2bf(-r.y * inv) << 16);
    *(unsigned*)(vs + 2 * j) = ov;
  }
}

// gate IN PLACE: u[bn][c] *= conv[c][bn]   (conv lives in vt)
__launch_bounds__(256)
__global__ void gate_trans(const ushort_t* __restrict__ convt, ushort_t* __restrict__ u)
{
  __shared__ ushort_t tile[64][65];
  const int bc = (int)blockIdx.x % 24, br = (int)blockIdx.x / 24;
  const int c0 = bc << 6, r0 = br << 6;
  const int tx = threadIdx.x & 63, ty = threadIdx.x >> 6;
  for (int yy = ty; yy < 64; yy += 4)
    tile[yy][tx] = convt[(long)(c0 + yy) * 16384 + r0 + tx];
  __syncthreads();
  for (int yy = ty; yy < 64; yy += 4) {
    long ui = (long)(r0 + yy) * 1536 + c0 + tx;
    float uu = bf2f(u[ui]);
    float cc = bf2f(tile[tx][yy]);
    u[ui] = f2bf(uu * cc);
  }
}

// ===========================================================================
extern "C" void kernel_launch(void* const* d_in, const int* in_sizes, int n_in,
                              void* d_out, int out_size, void* d_ws, size_t ws_size,
                              hipStream_t stream)
{
  const float* x     = (const float*)d_in[0];
  const float* Wu    = (const float*)d_in[1];
  const float* bu    = (const float*)d_in[2];
  const float* Wv    = (const float*)d_in[3];
  const float* bv    = (const float*)d_in[4];
  const float* Wo    = (const float*)d_in[5];
  const float* bo    = (const float*)d_in[6];
  const float* rWin  = (const float*)d_in[7];
  const float* rbin  = (const float*)d_in[8];
  const float* rW    = (const float*)d_in[9];
  const float* rb    = (const float*)d_in[10];
  const float* rWout = (const float*)d_in[11];
  const float* rbout = (const float*)d_in[12];

  char* base = (char*)d_ws;
  size_t off = 0;
  auto alloc = [&](size_t bytes) -> char* {
    size_t r = (off + 255) & ~(size_t)255; off = r + bytes; return base + r;
  };
  ushort_t* wuvt   = (ushort_t*)alloc(3072L * 512 * 2);     // [Wu^T; Wv^T]  3MB
  ushort_t* wot    = (ushort_t*)alloc(512L * 1536 * 2);     // Wo^T        1.5MB
  ushort_t* wrt    = (ushort_t*)alloc(3L * 512 * 512 * 2);  // rpe_W^T x3  1.5MB
  ushort_t* wroutt = (ushort_t*)alloc(1536L * 512 * 2);     // rpe_Wout^T  1.5MB
  float*    buvb   = (float*)   alloc(3072L * 4);           // [bu;bv]
  ushort_t* a0     = (ushort_t*)alloc(2048L * 512 * 2);     // RPE act bf16  2MB
  float2*   af     = (float2*)  alloc(1536L * 2052 * 8);    // spectra    25.2MB
  char*     X      = alloc(16384L * 512 * 2);               // xb | (h+kern) 16MB
  ushort_t* u      = (ushort_t*)alloc(16384L * 1536 * 2);   // u (later gated) 48MB
  ushort_t* vt     = (ushort_t*)alloc(1536L * 16384 * 2);   // v^T / conv^T  48MB
  // X region time-share: phase1 xb (16MB); phase2 h (4MB) + kern (12MB)
  ushort_t* xb   = (ushort_t*)X;
  float*    h    = (float*)X;
  float*    kern = (float*)(X + 4L * 1024 * 1024);

  const float lng = -0.01005033585350145f;   // ln(0.99)

  // ---- weight prep ----
  wtrans<<<dim3(768), dim3(256), 0, stream>>>(Wu, wuvt, 512, 1536);
  wtrans<<<dim3(768), dim3(256), 0, stream>>>(Wv, wuvt + 1536L * 512, 512, 1536);
  wtrans<<<dim3(768), dim3(256), 0, stream>>>(Wo, wot, 1536, 512);
  for (int i = 0; i < 3; ++i)
    wtrans<<<dim3(256), dim3(256), 0, stream>>>(rW + (long)i * 512 * 512,
                                                wrt + (long)i * 512 * 512, 512, 512);
  wtrans<<<dim3(768), dim3(256), 0, stream>>>(rWout, wroutt, 512, 1536);
  concat_bias<<<dim3(6), dim3(256), 0, stream>>>(bu, bv, buvb);
  cvt_bf16<<<dim3(8192), dim3(256), 0, stream>>>(x, xb);

  // ---- u/v projection (fused, v stored transposed) -- uses xb, then xb dead
  gemm_bt<3><<<dim3(3072), dim3(256), 0, stream>>>(xb, wuvt, buvb, u, vt,
                                                   16384, 3072, 512, 0.f);

  // ---- RPE chain -> kern[c][n] -> spectra af (h/kern overlay the xb region)
  rpe_h0<<<dim3(2048), dim3(256), 0, stream>>>(rWin, rbin, a0);
  for (int i = 0; i < 3; ++i) {
    gemm_bt<0><<<dim3(64), dim3(256), 0, stream>>>(a0, wrt + (long)i * 512 * 512,
                                                   rb + (long)i * 512, h, nullptr,
                                                   2048, 512, 512, 0.f);
    rpe_norm<<<dim3(2048), dim3(256), 0, stream>>>(h, a0);
  }
  gemm_bt<2><<<dim3(192), dim3(256), 0, stream>>>(a0, wroutt, rbout, kern, nullptr,
                                                  2048, 1536, 512, lng);
  fft_kernel_spec<<<dim3(1536), dim3(256), 0, stream>>>(kern, af);

  // ---- FFT conv in place on vt, gate in place into u, out projection ----
  fft_conv<<<dim3(12288), dim3(256), 0, stream>>>(vt, af);
  gate_trans<<<dim3(6144), dim3(256), 0, stream>>>(vt, u);
  gemm_bt<0><<<dim3(512), dim3(256), 0, stream>>>(u, wot, bo, d_out, nullptr,
                                                  16384, 512, 1536, 0.f);
}

// Round 3
// 530.795 us; speedup vs baseline: 1.0550x; 1.0550x over previous
//
#include <hip/hip_runtime.h>
#include <cstdint>

// ============================================================================
// Gtu: u=silu(x@Wu+bu); v=silu(x@Wv+bv); per-channel causal conv of v with
// RPE-generated decayed kernel (rfft4096 via packed cfft2048); out=(u*conv)@Wo+bo
// R3: fft kernels -> 32KB LDS (tw moved to global, precomputed), XOR bank
// swizzle on all FFT LDS accesses, prep kernels merged into one dispatch.
// ============================================================================

typedef unsigned short ushort_t;                                    // bf16 bits
typedef __attribute__((ext_vector_type(8))) short short8;           // MFMA A/B frag
typedef __attribute__((ext_vector_type(4))) float f32x4;            // MFMA acc

#define AS1 __attribute__((address_space(1)))
#define AS3 __attribute__((address_space(3)))

// Bank swizzle for float2 LDS arrays: inject bits 5-7 into bank bits 1-3.
// Bijection on [0,2048); keeps bit0 (float2 pairs from radix-2 stay adjacent).
#define SWZ(j) ((j) ^ (((j) >> 4) & 14))

__device__ __forceinline__ float bf2f(ushort_t b) {
  union { unsigned u; float f; } x; x.u = ((unsigned)b) << 16; return x.f;
}
__device__ __forceinline__ ushort_t f2bf(float f) {
  union { float f; unsigned u; } x; x.f = f;
  unsigned r = x.u + 0x7fffu + ((x.u >> 16) & 1u);   // RNE
  return (ushort_t)(r >> 16);
}

// CK-style addrspace cast (flat LDS addr low 32 bits == LDS offset on gfx9)
__device__ __forceinline__ void gload_lds16(const void* g, void* l) {
  auto gp = reinterpret_cast<const AS1 unsigned*>(reinterpret_cast<uintptr_t>(g));
  auto lp = reinterpret_cast<AS3 unsigned*>(reinterpret_cast<uintptr_t>(l));
  __builtin_amdgcn_global_load_lds(gp, lp, 16, 0, 0);
}

// ---------------------------------------------------------------------------
// bf16 GEMM: C = A[M][K] @ Bt[N][K]^T (+bias). 128x128x64 tiles, 4 waves.
// MODE 0: fp32 store to Cout[M][N].
// MODE 2: val*gamma^row, fp32 store transposed Cout[col*M+row]  (RPE kernel).
// MODE 3: silu; col<1536 -> bf16 Cout[row*1536+col] (u);
//               col>=1536 -> bf16 Cout2[(col-1536)*16384+row] (v transposed).
// ---------------------------------------------------------------------------
template<int MODE>
__launch_bounds__(256, 2)
__global__ void gemm_bt(const ushort_t* __restrict__ A, const ushort_t* __restrict__ Bt,
                        const float* __restrict__ bias, void* __restrict__ Cout,
                        void* __restrict__ Cout2, int M, int N, int K, float lng)
{
  __shared__ ushort_t As[128 * 64];
  __shared__ ushort_t Bs[128 * 64];
  const int tid  = threadIdx.x;
  const int wave = tid >> 6, lane = tid & 63;
  const int nb = N >> 7;
  const int bm = (int)blockIdx.x / nb, bn = (int)blockIdx.x % nb;
  const int m0 = bm << 7, n0 = bn << 7;
  const int lrow = lane & 15, quad = lane >> 4;
  const int wm = (wave >> 1) << 6, wn = (wave & 1) << 6;
  const int srow = lane >> 3;            // 0..7 (row within 8-row chunk)
  const int scol = (lane & 7) << 3;      // bf16 col (8-elem granules)

  f32x4 acc[4][4] = {};

  for (int kt = 0; kt < K; kt += 64) {
    __syncthreads();
#pragma unroll
    for (int i = 0; i < 4; ++i) {
      const int ci  = i * 4 + wave;      // chunk 0..15, wave-uniform
      const int row = ci * 8 + srow;
      gload_lds16(A  + (long)(m0 + row) * K + kt + scol, (void*)&As[ci * 512]);
      gload_lds16(Bt + (long)(n0 + row) * K + kt + scol, (void*)&Bs[ci * 512]);
    }
    __syncthreads();   // compiler drains vmcnt before s_barrier
#pragma unroll
    for (int s = 0; s < 2; ++s) {
      short8 afr[4], bfr[4];
#pragma unroll
      for (int i = 0; i < 4; ++i)
        afr[i] = *(const short8*)&As[(wm + i * 16 + lrow) * 64 + s * 32 + quad * 8];
#pragma unroll
      for (int j = 0; j < 4; ++j)
        bfr[j] = *(const short8*)&Bs[(wn + j * 16 + lrow) * 64 + s * 32 + quad * 8];
#pragma unroll
      for (int i = 0; i < 4; ++i)
#pragma unroll
        for (int j = 0; j < 4; ++j)
          acc[i][j] = __builtin_amdgcn_mfma_f32_16x16x32_bf16(afr[i], bfr[j], acc[i][j], 0, 0, 0);
    }
  }

#pragma unroll
  for (int i = 0; i < 4; ++i) {
    const int rowb = m0 + wm + i * 16 + quad * 4;
#pragma unroll
    for (int j = 0; j < 4; ++j) {
      const int col = n0 + wn + j * 16 + lrow;
      const float bv = bias[col];
      if (MODE == 0) {
#pragma unroll
        for (int r = 0; r < 4; ++r)
          ((float*)Cout)[(long)(rowb + r) * N + col] = acc[i][j][r] + bv;
      } else if (MODE == 2) {
#pragma unroll
        for (int r = 0; r < 4; ++r) {
          const int row = rowb + r;
          float dec = __expf(lng * (float)row);           // gamma^row
          ((float*)Cout)[(long)col * M + row] = (acc[i][j][r] + bv) * dec;
        }
      } else {  // MODE 3
        if (col < 1536) {
#pragma unroll
          for (int r = 0; r < 4; ++r) {
            float val = acc[i][j][r] + bv;
            float sv = val / (1.f + __expf(-val));
            ((ushort_t*)Cout)[(long)(rowb + r) * 1536 + col] = f2bf(sv);
          }
        } else {
          union { ushort_t h[4]; uint2 u2; } pk;
#pragma unroll
          for (int r = 0; r < 4; ++r) {
            float val = acc[i][j][r] + bv;
            float sv = val / (1.f + __expf(-val));
            pk.h[r] = f2bf(sv);
          }
          *(uint2*)((ushort_t*)Cout2 + (long)(col - 1536) * 16384 + rowb) = pk.u2;
        }
      }
    }
  }
}

// ---------------------------------------------------------------------------
// RPE row op: srms -> relu -> bf16 (one 256-thr block per row of 512)
// ---------------------------------------------------------------------------
__device__ __forceinline__ void srms_relu_store(float v0, float v1, ushort_t* out,
                                                long rowbase, int tid)
{
  float ss = v0 * v0 + v1 * v1;
#pragma unroll
  for (int off = 32; off; off >>= 1) ss += __shfl_down(ss, off);
  __shared__ float ps[4];
  const int wave = tid >> 6, lane = tid & 63;
  if (lane == 0) ps[wave] = ss;
  __syncthreads();
  float tot = ps[0] + ps[1] + ps[2] + ps[3];
  float sc = 1.f / (sqrtf(tot * (1.f / 512.f)) + 1e-6f);
  out[rowbase + tid]       = f2bf(fmaxf(v0 * sc, 0.f));
  out[rowbase + tid + 256] = f2bf(fmaxf(v1 * sc, 0.f));
}

__launch_bounds__(256)
__global__ void rpe_norm(const float* __restrict__ h, ushort_t* __restrict__ out)
{
  const int n = blockIdx.x, tid = threadIdx.x;
  float v0 = h[(long)n * 512 + tid];
  float v1 = h[(long)n * 512 + tid + 256];
  srms_relu_store(v0, v1, out, (long)n * 512, tid);
}

// ---------------------------------------------------------------------------
// Merged prep: 6x weight transpose | bias concat | x->bf16 | twiddles | rpe_h0
// Block role by blockIdx range; all branches block-uniform.
// ---------------------------------------------------------------------------
__device__ __forceinline__ void wtrans_body(const float* __restrict__ src,
                                            ushort_t* __restrict__ dst,
                                            int K, int N, int lb, int tid,
                                            float (*tile)[33])
{
  const int nbx = N >> 5;
  const int bx = lb % nbx, by = lb / nbx;
  const int n0 = bx << 5, k0 = by << 5;
  const int tx = tid & 31, ty = tid >> 5;   // ty 0..7
  for (int yy = ty; yy < 32; yy += 8)
    tile[yy][tx] = src[(long)(k0 + yy) * N + n0 + tx];
  __syncthreads();
  for (int yy = ty; yy < 32; yy += 8)
    dst[(long)(n0 + yy) * K + k0 + tx] = f2bf(tile[tx][yy]);
}

__launch_bounds__(256)
__global__ void prep_all(const float* __restrict__ Wu, const float* __restrict__ Wv,
                         const float* __restrict__ Wo, const float* __restrict__ rW,
                         const float* __restrict__ rWout,
                         const float* __restrict__ bu, const float* __restrict__ bv,
                         const float* __restrict__ x,
                         const float* __restrict__ rWin, const float* __restrict__ rbin,
                         ushort_t* __restrict__ wuvt, ushort_t* __restrict__ wot,
                         ushort_t* __restrict__ wrt, ushort_t* __restrict__ wroutt,
                         float* __restrict__ buvb, ushort_t* __restrict__ xb,
                         float2* __restrict__ twg, float2* __restrict__ twh,
                         ushort_t* __restrict__ a0)
{
  __shared__ float tile[32][33];
  const int bid = blockIdx.x, tid = threadIdx.x;
  if (bid < 3840) {                       // ---- weight transposes ----
    const float* src; ushort_t* dst; int K, N, lb;
    if (bid < 768)       { src = Wu;    dst = wuvt;              K = 512;  N = 1536; lb = bid; }
    else if (bid < 1536) { src = Wv;    dst = wuvt + 1536L*512;  K = 512;  N = 1536; lb = bid - 768; }
    else if (bid < 2304) { src = Wo;    dst = wot;               K = 1536; N = 512;  lb = bid - 1536; }
    else if (bid < 2560) { src = rW;              dst = wrt;              K = 512; N = 512; lb = bid - 2304; }
    else if (bid < 2816) { src = rW + 512L*512;   dst = wrt + 512L*512;   K = 512; N = 512; lb = bid - 2560; }
    else if (bid < 3072) { src = rW + 2L*512*512; dst = wrt + 2L*512*512; K = 512; N = 512; lb = bid - 2816; }
    else                 { src = rWout; dst = wroutt;            K = 512;  N = 1536; lb = bid - 3072; }
    wtrans_body(src, dst, K, N, lb, tid, tile);
  } else if (bid < 3846) {                // ---- bias concat ----
    int i = (bid - 3840) * 256 + tid;
    if (i < 1536) { buvb[i] = bu[i]; buvb[1536 + i] = bv[i]; }
  } else if (bid < 12038) {               // ---- x -> bf16 ----
    long i = (long)(bid - 3846) * 1024 + tid * 4;
    float4 f = *(const float4*)(x + i);
    unsigned lo = (unsigned)f2bf(f.x) | ((unsigned)f2bf(f.y) << 16);
    unsigned hi = (unsigned)f2bf(f.z) | ((unsigned)f2bf(f.w) << 16);
    *(uint2*)(xb + i) = make_uint2(lo, hi);
  } else if (bid < 12046) {               // ---- twiddle tables ----
    int j = (bid - 12038) * 256 + tid;    // 0..2047
    float s, c;
    __sincosf((float)j * (6.283185307179586f / 2048.f), &s, &c);
    twg[j] = make_float2(c, -s);
    if (j <= 1024) {
      float s2, c2;
      __sincosf((float)j * (3.14159265358979f / 2048.f), &s2, &c2);
      twh[j] = make_float2(c2, -s2);
    }
  } else {                                // ---- rpe_h0 ----
    const int n = bid - 12046;            // 0..2047
    const float fn = (float)n;
    float v0 = fn * rWin[tid] + rbin[tid];
    float v1 = fn * rWin[tid + 256] + rbin[tid + 256];
    srms_relu_store(v0, v1, a0, (long)n * 512, tid);
  }
}

// ---------------------------------------------------------------------------
// In-LDS 2048-pt complex FFT (Stockham: radix-2 then 5x radix-4), XOR-swizzled
// LDS addressing, twiddles from global. Input arg0, scratch arg1, result arg0.
// ---------------------------------------------------------------------------
__device__ __forceinline__ float2 cmulf(float2 a, float2 b) {
  return make_float2(a.x * b.x - a.y * b.y, a.x * b.y + a.y * b.x);
}

__device__ void fft2048_lds(float2* bx, float2* by, const float2* __restrict__ tw, int tid)
{
#pragma unroll
  for (int ii = 0; ii < 4; ++ii) {             // radix-2, p=1
    const int i = tid + ii * 256;
    float2 a = bx[SWZ(i)], b = bx[SWZ(i + 1024)];
    const int s = SWZ(2 * i);                  // SWZ keeps bit0: pair adjacent
    by[s]     = make_float2(a.x + b.x, a.y + b.y);
    by[s + 1] = make_float2(a.x - b.x, a.y - b.y);
  }
  __syncthreads();
  float2* src = by; float2* dst = bx;
#pragma unroll
  for (int ps = 0; ps < 5; ++ps) {             // radix-4, p = 2,8,32,128,512
    const int p = 2 << (2 * ps);
    const int ts = 512 / p;
#pragma unroll
    for (int ii = 0; ii < 2; ++ii) {
      const int i = tid + ii * 256;
      const int k = i & (p - 1);
      float2 u0 = src[SWZ(i)],        u1 = src[SWZ(i + 512)];
      float2 u2 = src[SWZ(i + 1024)], u3 = src[SWZ(i + 1536)];
      const int tb = k * ts;
      float2 w1 = tw[tb], w2 = tw[2 * tb], w3 = tw[3 * tb];
      u1 = cmulf(u1, w1); u2 = cmulf(u2, w2); u3 = cmulf(u3, w3);
      float2 v0 = make_float2(u0.x + u2.x, u0.y + u2.y);
      float2 v2 = make_float2(u0.x - u2.x, u0.y - u2.y);
      float2 v1 = make_float2(u1.x + u3.x, u1.y + u3.y);
      float2 v3 = make_float2(u1.y - u3.y, u3.x - u1.x);   // (u1-u3)*(-i)
      const int j = ((i - k) << 2) + k;
      dst[SWZ(j)]         = make_float2(v0.x + v1.x, v0.y + v1.y);
      dst[SWZ(j + p)]     = make_float2(v2.x + v3.x, v2.y + v3.y);
      dst[SWZ(j + 2*p)]   = make_float2(v0.x - v1.x, v0.y - v1.y);
      dst[SWZ(j + 3*p)]   = make_float2(v2.x - v3.x, v2.y - v3.y);
    }
    __syncthreads();
    float2* t = src; src = dst; dst = t;
  }
}

// Kernel spectrum: af[c][k] = rfft_4096(kern[c][0:2048] zero-padded), k=0..2048
__launch_bounds__(256)
__global__ void fft_kernel_spec(const float* __restrict__ kern, float2* __restrict__ af,
                                const float2* __restrict__ twg, const float2* __restrict__ twh)
{
  __shared__ float2 bx[2048], by[2048];
  const int tid = threadIdx.x, c = blockIdx.x;
  const float* kc = kern + (long)c * 2048;
  for (int j = tid; j < 1024; j += 256) bx[SWZ(j)] = *(const float2*)(kc + 2 * j);
  for (int j = tid + 1024; j < 2048; j += 256) bx[SWZ(j)] = make_float2(0.f, 0.f);
  __syncthreads();
  fft2048_lds(bx, by, twg, tid);
  float2* afc = af + (long)c * 2052;
  for (int k = tid; k <= 1024; k += 256) {
    float2 Zk = bx[SWZ(k)], Zn = bx[SWZ((2048 - k) & 2047)];
    float2 E = make_float2(0.5f * (Zk.x + Zn.x), 0.5f * (Zk.y - Zn.y));
    float2 O = make_float2(0.5f * (Zk.y + Zn.y), 0.5f * (Zn.x - Zk.x));
    float2 W = twh[k];
    float2 WO = cmulf(W, O);
    afc[k] = make_float2(E.x + WO.x, E.y + WO.y);
    if (k != 0 && k != 1024)
      afc[2048 - k] = make_float2(E.x - WO.x, -(E.y - WO.y));
    if (k == 0)
      afc[2048] = make_float2(E.x - WO.x, -(E.y - WO.y));
  }
}

// Conv (IN PLACE on vt): y = irfft4096(rfft4096(v)*af)[0:2048], block=(c,b) seq
__launch_bounds__(256)
__global__ void fft_conv(ushort_t* __restrict__ vt, const float2* __restrict__ af,
                         const float2* __restrict__ twg, const float2* __restrict__ twh)
{
  __shared__ float2 bx[2048], by[2048];
  const int tid = threadIdx.x;
  const int c = (int)blockIdx.x >> 3;
  ushort_t* vs = vt + (long)blockIdx.x * 2048;
  for (int j = tid; j < 1024; j += 256) {
    unsigned pv = *(const unsigned*)(vs + 2 * j);
    bx[SWZ(j)] = make_float2(bf2f((ushort_t)(pv & 0xffffu)), bf2f((ushort_t)(pv >> 16)));
  }
  for (int j = tid + 1024; j < 2048; j += 256) bx[SWZ(j)] = make_float2(0.f, 0.f);
  __syncthreads();
  fft2048_lds(bx, by, twg, tid);                // bx = Z (packed fwd FFT)
  const float2* afc = af + (long)c * 2052;
  for (int k = tid; k <= 1024; k += 256) {
    float2 Zk = bx[SWZ(k)], Zn = bx[SWZ((2048 - k) & 2047)];
    float2 E = make_float2(0.5f * (Zk.x + Zn.x), 0.5f * (Zk.y - Zn.y));
    float2 O = make_float2(0.5f * (Zk.y + Zn.y), 0.5f * (Zn.x - Zk.x));
    float2 W = twh[k];
    float2 WO = cmulf(W, O);
    float2 Xk = make_float2(E.x + WO.x, E.y + WO.y);          // rfft(v)[k]
    float2 Xn = make_float2(E.x - WO.x, -(E.y - WO.y));       // rfft(v)[2048-k]
    float2 Pk = cmulf(Xk, afc[k]);
    float2 Pn = cmulf(Xn, afc[2048 - k]);
    // E2=(Pk+conj(Pn))/2, G=(Pk-conj(Pn))/2, Fo=conj(W)*G, W2=E2+i*Fo
    float2 E2 = make_float2(0.5f * (Pk.x + Pn.x), 0.5f * (Pk.y - Pn.y));
    float2 G  = make_float2(0.5f * (Pk.x - Pn.x), 0.5f * (Pk.y + Pn.y));
    float2 cW = make_float2(W.x, -W.y);
    float2 Fo = cmulf(cW, G);
    by[SWZ(k)] = make_float2(E2.x - Fo.y, -(E2.y + Fo.x));     // conj(W2[k])
    if (k != 0 && k != 1024) {
      const int kn = 2048 - k;
      by[SWZ(kn)] = make_float2(E2.x + Fo.y, E2.y - Fo.x);     // conj(W2[2048-k])
    }
  }
  __syncthreads();
  fft2048_lds(by, bx, twg, tid);                // by = FFT(conj(W2))
  const float inv = 1.f / 2048.f;
  for (int j = tid; j < 1024; j += 256) {       // z[j]=conj(by[j])/2048
    float2 r = by[SWZ(j)];
    unsigned ov = (unsigned)f2bf(r.x * inv) | ((unsigned)f2bf(-r.y * inv) << 16);
    *(unsigned*)(vs + 2 * j) = ov;
  }
}

// gate IN PLACE: u[bn][c] *= conv[c][bn]   (conv lives in vt)
__launch_bounds__(256)
__global__ void gate_trans(const ushort_t* __restrict__ convt, ushort_t* __restrict__ u)
{
  __shared__ ushort_t tile[64][65];
  const int bc = (int)blockIdx.x % 24, br = (int)blockIdx.x / 24;
  const int c0 = bc << 6, r0 = br << 6;
  const int tx = threadIdx.x & 63, ty = threadIdx.x >> 6;
  for (int yy = ty; yy < 64; yy += 4)
    tile[yy][tx] = convt[(long)(c0 + yy) * 16384 + r0 + tx];
  __syncthreads();
  for (int yy = ty; yy < 64; yy += 4) {
    long ui = (long)(r0 + yy) * 1536 + c0 + tx;
    float uu = bf2f(u[ui]);
    float cc = bf2f(tile[tx][yy]);
    u[ui] = f2bf(uu * cc);
  }
}

// ===========================================================================
extern "C" void kernel_launch(void* const* d_in, const int* in_sizes, int n_in,
                              void* d_out, int out_size, void* d_ws, size_t ws_size,
                              hipStream_t stream)
{
  const float* x     = (const float*)d_in[0];
  const float* Wu    = (const float*)d_in[1];
  const float* bu    = (const float*)d_in[2];
  const float* Wv    = (const float*)d_in[3];
  const float* bv    = (const float*)d_in[4];
  const float* Wo    = (const float*)d_in[5];
  const float* bo    = (const float*)d_in[6];
  const float* rWin  = (const float*)d_in[7];
  const float* rbin  = (const float*)d_in[8];
  const float* rW    = (const float*)d_in[9];
  const float* rb    = (const float*)d_in[10];
  const float* rWout = (const float*)d_in[11];
  const float* rbout = (const float*)d_in[12];

  char* base = (char*)d_ws;
  size_t off = 0;
  auto alloc = [&](size_t bytes) -> char* {
    size_t r = (off + 255) & ~(size_t)255; off = r + bytes; return base + r;
  };
  ushort_t* wuvt   = (ushort_t*)alloc(3072L * 512 * 2);     // [Wu^T; Wv^T]  3MB
  ushort_t* wot    = (ushort_t*)alloc(512L * 1536 * 2);     // Wo^T        1.5MB
  ushort_t* wrt    = (ushort_t*)alloc(3L * 512 * 512 * 2);  // rpe_W^T x3  1.5MB
  ushort_t* wroutt = (ushort_t*)alloc(1536L * 512 * 2);     // rpe_Wout^T  1.5MB
  float*    buvb   = (float*)   alloc(3072L * 4);           // [bu;bv]
  ushort_t* a0     = (ushort_t*)alloc(2048L * 512 * 2);     // RPE act bf16  2MB
  float2*   af     = (float2*)  alloc(1536L * 2052 * 8);    // spectra    25.2MB
  float2*   twg    = (float2*)  alloc(2048L * 8);           // cis(-2pi j/2048)
  float2*   twh    = (float2*)  alloc(1025L * 8);           // cis(-pi k/2048)
  char*     X      = alloc(16384L * 512 * 2);               // xb | (h+kern) 16MB
  ushort_t* u      = (ushort_t*)alloc(16384L * 1536 * 2);   // u (later gated) 48MB
  ushort_t* vt     = (ushort_t*)alloc(1536L * 16384 * 2);   // v^T / conv^T  48MB
  // X region time-share: phase1 xb (16MB); phase2 h (4MB) + kern (12MB)
  ushort_t* xb   = (ushort_t*)X;
  float*    h    = (float*)X;
  float*    kern = (float*)(X + 4L * 1024 * 1024);

  const float lng = -0.01005033585350145f;   // ln(0.99)

  // ---- merged prep: weights, biases, x->bf16, twiddles, rpe_h0 ----
  prep_all<<<dim3(14094), dim3(256), 0, stream>>>(
      Wu, Wv, Wo, rW, rWout, bu, bv, x, rWin, rbin,
      wuvt, wot, wrt, wroutt, buvb, xb, twg, twh, a0);

  // ---- u/v projection (fused, v stored transposed) -- uses xb, then xb dead
  gemm_bt<3><<<dim3(3072), dim3(256), 0, stream>>>(xb, wuvt, buvb, u, vt,
                                                   16384, 3072, 512, 0.f);

  // ---- RPE chain -> kern[c][n] -> spectra af (h/kern overlay the xb region)
  for (int i = 0; i < 3; ++i) {
    gemm_bt<0><<<dim3(64), dim3(256), 0, stream>>>(a0, wrt + (long)i * 512 * 512,
                                                   rb + (long)i * 512, h, nullptr,
                                                   2048, 512, 512, 0.f);
    rpe_norm<<<dim3(2048), dim3(256), 0, stream>>>(h, a0);
  }
  gemm_bt<2><<<dim3(192), dim3(256), 0, stream>>>(a0, wroutt, rbout, kern, nullptr,
                                                  2048, 1536, 512, lng);
  fft_kernel_spec<<<dim3(1536), dim3(256), 0, stream>>>(kern, af, twg, twh);

  // ---- FFT conv in place on vt, gate in place into u, out projection ----
  fft_conv<<<dim3(12288), dim3(256), 0, stream>>>(vt, af, twg, twh);
  gate_trans<<<dim3(6144), dim3(256), 0, stream>>>(vt, u);
  gemm_bt<0><<<dim3(512), dim3(256), 0, stream>>>(u, wot, bo, d_out, nullptr,
                                                  16384, 512, 1536, 0.f);
}

// Round 4
// 511.032 us; speedup vs baseline: 1.0958x; 1.0387x over previous
//
#include <hip/hip_runtime.h>
#include <cstdint>

// ============================================================================
// Gtu: u=silu(x@Wu+bu); v=silu(x@Wv+bv); per-channel causal conv of v with
// RPE-generated decayed kernel (rfft4096 via packed cfft2048); out=(u*conv)@Wo+bo
// R4: FFT rewritten as register-based Stockham radix-8,8,8,4 (4 LDS round
// trips vs 6; stage-1 twiddle-free; zero-pad-aware forward). Per-stage XOR
// swizzles keep every LDS op at the even 4-dword/bank minimum.
// ============================================================================

typedef unsigned short ushort_t;                                    // bf16 bits
typedef __attribute__((ext_vector_type(8))) short short8;           // MFMA A/B frag
typedef __attribute__((ext_vector_type(4))) float f32x4;            // MFMA acc

#define AS1 __attribute__((address_space(1)))
#define AS3 __attribute__((address_space(3)))

// per-buffer swizzles (bijections on [0,2048) float2 indices)
#define SW1(j) ((j) ^ (((j) >> 4) & 15))        // stage1-output buffer
#define SW2(j) ((j) ^ ((((j) >> 6) & 7) << 1))  // stage2-output buffer

__device__ __forceinline__ float bf2f(ushort_t b) {
  union { unsigned u; float f; } x; x.u = ((unsigned)b) << 16; return x.f;
}
__device__ __forceinline__ ushort_t f2bf(float f) {
  union { float f; unsigned u; } x; x.f = f;
  unsigned r = x.u + 0x7fffu + ((x.u >> 16) & 1u);   // RNE
  return (ushort_t)(r >> 16);
}

// CK-style addrspace cast (flat LDS addr low 32 bits == LDS offset on gfx9)
__device__ __forceinline__ void gload_lds16(const void* g, void* l) {
  auto gp = reinterpret_cast<const AS1 unsigned*>(reinterpret_cast<uintptr_t>(g));
  auto lp = reinterpret_cast<AS3 unsigned*>(reinterpret_cast<uintptr_t>(l));
  __builtin_amdgcn_global_load_lds(gp, lp, 16, 0, 0);
}

// ---------------------------------------------------------------------------
// bf16 GEMM: C = A[M][K] @ Bt[N][K]^T (+bias). 128x128x64 tiles, 4 waves.
// MODE 0: fp32 store. MODE 2: *gamma^row, fp32 transposed store (RPE kernel).
// MODE 3: silu; col<1536 -> u[row][col] bf16; col>=1536 -> vt[col-1536][row].
// ---------------------------------------------------------------------------
template<int MODE>
__launch_bounds__(256, 2)
__global__ void gemm_bt(const ushort_t* __restrict__ A, const ushort_t* __restrict__ Bt,
                        const float* __restrict__ bias, void* __restrict__ Cout,
                        void* __restrict__ Cout2, int M, int N, int K, float lng)
{
  __shared__ ushort_t As[128 * 64];
  __shared__ ushort_t Bs[128 * 64];
  const int tid  = threadIdx.x;
  const int wave = tid >> 6, lane = tid & 63;
  const int nb = N >> 7;
  const int bm = (int)blockIdx.x / nb, bn = (int)blockIdx.x % nb;
  const int m0 = bm << 7, n0 = bn << 7;
  const int lrow = lane & 15, quad = lane >> 4;
  const int wm = (wave >> 1) << 6, wn = (wave & 1) << 6;
  const int srow = lane >> 3;            // 0..7 (row within 8-row chunk)
  const int scol = (lane & 7) << 3;      // bf16 col (8-elem granules)

  f32x4 acc[4][4] = {};

  for (int kt = 0; kt < K; kt += 64) {
    __syncthreads();
#pragma unroll
    for (int i = 0; i < 4; ++i) {
      const int ci  = i * 4 + wave;      // chunk 0..15, wave-uniform
      const int row = ci * 8 + srow;
      gload_lds16(A  + (long)(m0 + row) * K + kt + scol, (void*)&As[ci * 512]);
      gload_lds16(Bt + (long)(n0 + row) * K + kt + scol, (void*)&Bs[ci * 512]);
    }
    __syncthreads();
#pragma unroll
    for (int s = 0; s < 2; ++s) {
      short8 afr[4], bfr[4];
#pragma unroll
      for (int i = 0; i < 4; ++i)
        afr[i] = *(const short8*)&As[(wm + i * 16 + lrow) * 64 + s * 32 + quad * 8];
#pragma unroll
      for (int j = 0; j < 4; ++j)
        bfr[j] = *(const short8*)&Bs[(wn + j * 16 + lrow) * 64 + s * 32 + quad * 8];
#pragma unroll
      for (int i = 0; i < 4; ++i)
#pragma unroll
        for (int j = 0; j < 4; ++j)
          acc[i][j] = __builtin_amdgcn_mfma_f32_16x16x32_bf16(afr[i], bfr[j], acc[i][j], 0, 0, 0);
    }
  }

#pragma unroll
  for (int i = 0; i < 4; ++i) {
    const int rowb = m0 + wm + i * 16 + quad * 4;
#pragma unroll
    for (int j = 0; j < 4; ++j) {
      const int col = n0 + wn + j * 16 + lrow;
      const float bv = bias[col];
      if (MODE == 0) {
#pragma unroll
        for (int r = 0; r < 4; ++r)
          ((float*)Cout)[(long)(rowb + r) * N + col] = acc[i][j][r] + bv;
      } else if (MODE == 2) {
#pragma unroll
        for (int r = 0; r < 4; ++r) {
          const int row = rowb + r;
          float dec = __expf(lng * (float)row);           // gamma^row
          ((float*)Cout)[(long)col * M + row] = (acc[i][j][r] + bv) * dec;
        }
      } else {  // MODE 3
        if (col < 1536) {
#pragma unroll
          for (int r = 0; r < 4; ++r) {
            float val = acc[i][j][r] + bv;
            float sv = val / (1.f + __expf(-val));
            ((ushort_t*)Cout)[(long)(rowb + r) * 1536 + col] = f2bf(sv);
          }
        } else {
          union { ushort_t h[4]; uint2 u2; } pk;
#pragma unroll
          for (int r = 0; r < 4; ++r) {
            float val = acc[i][j][r] + bv;
            float sv = val / (1.f + __expf(-val));
            pk.h[r] = f2bf(sv);
          }
          *(uint2*)((ushort_t*)Cout2 + (long)(col - 1536) * 16384 + rowb) = pk.u2;
        }
      }
    }
  }
}

// ---------------------------------------------------------------------------
// RPE row op: srms -> relu -> bf16 (one 256-thr block per row of 512)
// ---------------------------------------------------------------------------
__device__ __forceinline__ void srms_relu_store(float v0, float v1, ushort_t* out,
                                                long rowbase, int tid)
{
  float ss = v0 * v0 + v1 * v1;
#pragma unroll
  for (int off = 32; off; off >>= 1) ss += __shfl_down(ss, off);
  __shared__ float ps[4];
  const int wave = tid >> 6, lane = tid & 63;
  if (lane == 0) ps[wave] = ss;
  __syncthreads();
  float tot = ps[0] + ps[1] + ps[2] + ps[3];
  float sc = 1.f / (sqrtf(tot * (1.f / 512.f)) + 1e-6f);
  out[rowbase + tid]       = f2bf(fmaxf(v0 * sc, 0.f));
  out[rowbase + tid + 256] = f2bf(fmaxf(v1 * sc, 0.f));
}

__launch_bounds__(256)
__global__ void rpe_norm(const float* __restrict__ h, ushort_t* __restrict__ out)
{
  const int n = blockIdx.x, tid = threadIdx.x;
  float v0 = h[(long)n * 512 + tid];
  float v1 = h[(long)n * 512 + tid + 256];
  srms_relu_store(v0, v1, out, (long)n * 512, tid);
}

// ---------------------------------------------------------------------------
// Merged prep: 6x weight transpose | bias concat | x->bf16 | twiddles | rpe_h0
// ---------------------------------------------------------------------------
__device__ __forceinline__ void wtrans_body(const float* __restrict__ src,
                                            ushort_t* __restrict__ dst,
                                            int K, int N, int lb, int tid,
                                            float (*tile)[33])
{
  const int nbx = N >> 5;
  const int bx = lb % nbx, by = lb / nbx;
  const int n0 = bx << 5, k0 = by << 5;
  const int tx = tid & 31, ty = tid >> 5;
  for (int yy = ty; yy < 32; yy += 8)
    tile[yy][tx] = src[(long)(k0 + yy) * N + n0 + tx];
  __syncthreads();
  for (int yy = ty; yy < 32; yy += 8)
    dst[(long)(n0 + yy) * K + k0 + tx] = f2bf(tile[tx][yy]);
}

__launch_bounds__(256)
__global__ void prep_all(const float* __restrict__ Wu, const float* __restrict__ Wv,
                         const float* __restrict__ Wo, const float* __restrict__ rW,
                         const float* __restrict__ rWout,
                         const float* __restrict__ bu, const float* __restrict__ bv,
                         const float* __restrict__ x,
                         const float* __restrict__ rWin, const float* __restrict__ rbin,
                         ushort_t* __restrict__ wuvt, ushort_t* __restrict__ wot,
                         ushort_t* __restrict__ wrt, ushort_t* __restrict__ wroutt,
                         float* __restrict__ buvb, ushort_t* __restrict__ xb,
                         float2* __restrict__ twg, float2* __restrict__ twh,
                         ushort_t* __restrict__ a0)
{
  __shared__ float tile[32][33];
  const int bid = blockIdx.x, tid = threadIdx.x;
  if (bid < 3840) {                       // ---- weight transposes ----
    const float* src; ushort_t* dst; int K, N, lb;
    if (bid < 768)       { src = Wu;    dst = wuvt;              K = 512;  N = 1536; lb = bid; }
    else if (bid < 1536) { src = Wv;    dst = wuvt + 1536L*512;  K = 512;  N = 1536; lb = bid - 768; }
    else if (bid < 2304) { src = Wo;    dst = wot;               K = 1536; N = 512;  lb = bid - 1536; }
    else if (bid < 2560) { src = rW;              dst = wrt;              K = 512; N = 512; lb = bid - 2304; }
    else if (bid < 2816) { src = rW + 512L*512;   dst = wrt + 512L*512;   K = 512; N = 512; lb = bid - 2560; }
    else if (bid < 3072) { src = rW + 2L*512*512; dst = wrt + 2L*512*512; K = 512; N = 512; lb = bid - 2816; }
    else                 { src = rWout; dst = wroutt;            K = 512;  N = 1536; lb = bid - 3072; }
    wtrans_body(src, dst, K, N, lb, tid, tile);
  } else if (bid < 3846) {                // ---- bias concat ----
    int i = (bid - 3840) * 256 + tid;
    if (i < 1536) { buvb[i] = bu[i]; buvb[1536 + i] = bv[i]; }
  } else if (bid < 12038) {               // ---- x -> bf16 ----
    long i = (long)(bid - 3846) * 1024 + tid * 4;
    float4 f = *(const float4*)(x + i);
    unsigned lo = (unsigned)f2bf(f.x) | ((unsigned)f2bf(f.y) << 16);
    unsigned hi = (unsigned)f2bf(f.z) | ((unsigned)f2bf(f.w) << 16);
    *(uint2*)(xb + i) = make_uint2(lo, hi);
  } else if (bid < 12046) {               // ---- twiddle tables ----
    int j = (bid - 12038) * 256 + tid;    // 0..2047
    float s, c;
    __sincosf((float)j * (6.283185307179586f / 2048.f), &s, &c);
    twg[j] = make_float2(c, -s);
    if (j <= 1024) {
      float s2, c2;
      __sincosf((float)j * (3.14159265358979f / 2048.f), &s2, &c2);
      twh[j] = make_float2(c2, -s2);
    }
  } else {                                // ---- rpe_h0 ----
    const int n = bid - 12046;            // 0..2047
    const float fn = (float)n;
    float v0 = fn * rWin[tid] + rbin[tid];
    float v1 = fn * rWin[tid + 256] + rbin[tid + 256];
    srms_relu_store(v0, v1, a0, (long)n * 512, tid);
  }
}

// ---------------------------------------------------------------------------
// Register-based Stockham FFT-2048: radix 8,8,8,4. 256 threads.
// Input in b0 (identity layout), scratch b1, OUTPUT in b0 (identity layout).
// tw[j] = cis(-2*pi*j/2048). HZ: input is zero for indices >= 1024.
// ---------------------------------------------------------------------------
__device__ __forceinline__ float2 cmulf(float2 a, float2 b) {
  return make_float2(a.x * b.x - a.y * b.y, a.x * b.y + a.y * b.x);
}
__device__ __forceinline__ float2 cadd(float2 a, float2 b){ return make_float2(a.x+b.x, a.y+b.y); }
__device__ __forceinline__ float2 csub(float2 a, float2 b){ return make_float2(a.x-b.x, a.y-b.y); }
__device__ __forceinline__ float2 cmni(float2 z){ return make_float2(z.y, -z.x); }     // z * (-i)
__device__ __forceinline__ float2 cw8(float2 z){   // z * cis(-pi/4)
  const float s = 0.70710678118654752f;
  return make_float2(s*(z.x+z.y), s*(z.y-z.x));
}
__device__ __forceinline__ float2 cw83(float2 z){  // z * cis(-3pi/4)
  const float s = 0.70710678118654752f;
  return make_float2(s*(z.y-z.x), -s*(z.x+z.y));
}

// DFT-8 combine (twiddles pre-applied). y[n] = sum_m u[m] w8^{nm}
__device__ __forceinline__ void dft8(const float2* u, float2* y)
{
  float2 a0=cadd(u[0],u[4]), a1=cadd(u[1],u[5]), a2=cadd(u[2],u[6]), a3=cadd(u[3],u[7]);
  float2 b0=csub(u[0],u[4]), b1=cw8(csub(u[1],u[5])), b2=cmni(csub(u[2],u[6])), b3=cw83(csub(u[3],u[7]));
  float2 c0=cadd(a0,a2), c1=csub(a0,a2), c2=cadd(a1,a3), c3=cmni(csub(a1,a3));
  y[0]=cadd(c0,c2); y[2]=cadd(c1,c3); y[4]=csub(c0,c2); y[6]=csub(c1,c3);
  float2 d0=cadd(b0,b2), d1=csub(b0,b2), d2=cadd(b1,b3), d3=cmni(csub(b1,b3));
  y[1]=cadd(d0,d2); y[3]=cadd(d1,d3); y[5]=csub(d0,d2); y[7]=csub(d1,d3);
}
// DFT-8 with u[4..7]=0
__device__ __forceinline__ void dft8_hz(const float2* u, float2* y)
{
  float2 b1=cw8(u[1]), b2=cmni(u[2]), b3=cw83(u[3]);
  float2 c0=cadd(u[0],u[2]), c1=csub(u[0],u[2]), c2=cadd(u[1],u[3]), c3=cmni(csub(u[1],u[3]));
  y[0]=cadd(c0,c2); y[2]=cadd(c1,c3); y[4]=csub(c0,c2); y[6]=csub(c1,c3);
  float2 d0=cadd(u[0],b2), d1=csub(u[0],b2), d2=cadd(b1,b3), d3=cmni(csub(b1,b3));
  y[1]=cadd(d0,d2); y[3]=cadd(d1,d3); y[5]=csub(d0,d2); y[7]=csub(d1,d3);
}

template<bool HZ>
__device__ void fft2048_r8(float2* b0, float2* b1, const float2* __restrict__ tw, int tid)
{
  float2 u[8], y[8];
  // stage 1: radix-8, p=1 (k=0 -> no twiddles). read b0[id], write b1[SW1].
  {
    const int i = tid;
#pragma unroll
    for (int m = 0; m < (HZ ? 4 : 8); ++m) u[m] = b0[i + 256 * m];
    if (HZ) dft8_hz(u, y); else dft8(u, y);
    const int j = i << 3;
#pragma unroll
    for (int m = 0; m < 8; ++m) b1[SW1(j + m)] = y[m];
  }
  __syncthreads();
  // stage 2: radix-8, p=8. read b1[SW1], write b0[SW2]. tw step 256/8=32.
  {
    const int i = tid, k = i & 7, tb = k << 5;
#pragma unroll
    for (int m = 0; m < 8; ++m) u[m] = b1[SW1(i + 256 * m)];
#pragma unroll
    for (int m = 1; m < 8; ++m) u[m] = cmulf(u[m], tw[m * tb]);
    dft8(u, y);
    const int j = ((i - k) << 3) + k;
#pragma unroll
    for (int m = 0; m < 8; ++m) b0[SW2(j + (m << 3))] = y[m];
  }
  __syncthreads();
  // stage 3: radix-8, p=64. read b0[SW2], write b1[id]. tw step 256/64=4.
  {
    const int i = tid, k = i & 63, tb = k << 2;
#pragma unroll
    for (int m = 0; m < 8; ++m) u[m] = b0[SW2(i + 256 * m)];
#pragma unroll
    for (int m = 1; m < 8; ++m) u[m] = cmulf(u[m], tw[m * tb]);
    dft8(u, y);
    const int j = ((i - k) << 3) + k;
#pragma unroll
    for (int m = 0; m < 8; ++m) b1[j + (m << 6)] = y[m];
  }
  __syncthreads();
  // stage 4: radix-4, p=512 (k=i, j=i). read b1[id], write b0[id].
#pragma unroll
  for (int h = 0; h < 2; ++h) {
    const int i = tid + (h << 8);
    float2 q0 = b1[i], q1 = b1[i + 512], q2 = b1[i + 1024], q3 = b1[i + 1536];
    q1 = cmulf(q1, tw[i]); q2 = cmulf(q2, tw[2 * i]); q3 = cmulf(q3, tw[3 * i]);
    float2 v0 = cadd(q0, q2), v2 = csub(q0, q2);
    float2 v1 = cadd(q1, q3), v3 = cmni(csub(q1, q3));
    b0[i]        = cadd(v0, v1);
    b0[i + 512]  = cadd(v2, v3);
    b0[i + 1024] = csub(v0, v1);
    b0[i + 1536] = csub(v2, v3);
  }
  __syncthreads();
}

// Kernel spectrum: af[c][k] = rfft_4096(kern[c][0:2048] zero-padded), k=0..2048
__launch_bounds__(256)
__global__ void fft_kernel_spec(const float* __restrict__ kern, float2* __restrict__ af,
                                const float2* __restrict__ twg, const float2* __restrict__ twh)
{
  __shared__ float2 bx[2048], by[2048];
  const int tid = threadIdx.x, c = blockIdx.x;
  const float* kc = kern + (long)c * 2048;
  for (int j = tid; j < 1024; j += 256) bx[j] = *(const float2*)(kc + 2 * j);
  __syncthreads();
  fft2048_r8<true>(bx, by, twg, tid);
  float2* afc = af + (long)c * 2052;
  for (int k = tid; k <= 1024; k += 256) {
    float2 Zk = bx[k], Zn = bx[(2048 - k) & 2047];
    float2 E = make_float2(0.5f * (Zk.x + Zn.x), 0.5f * (Zk.y - Zn.y));
    float2 O = make_float2(0.5f * (Zk.y + Zn.y), 0.5f * (Zn.x - Zk.x));
    float2 W = twh[k];
    float2 WO = cmulf(W, O);
    afc[k] = make_float2(E.x + WO.x, E.y + WO.y);
    if (k != 0 && k != 1024)
      afc[2048 - k] = make_float2(E.x - WO.x, -(E.y - WO.y));
    if (k == 0)
      afc[2048] = make_float2(E.x - WO.x, -(E.y - WO.y));
  }
}

// Conv (IN PLACE on vt): y = irfft4096(rfft4096(v)*af)[0:2048], block=(c,b) seq
__launch_bounds__(256)
__global__ void fft_conv(ushort_t* __restrict__ vt, const float2* __restrict__ af,
                         const float2* __restrict__ twg, const float2* __restrict__ twh)
{
  __shared__ float2 bx[2048], by[2048];
  const int tid = threadIdx.x;
  const int c = (int)blockIdx.x >> 3;
  ushort_t* vs = vt + (long)blockIdx.x * 2048;
#pragma unroll
  for (int jj = 0; jj < 4; ++jj) {
    const int j = tid + jj * 256;
    unsigned pv = *(const unsigned*)(vs + 2 * j);
    bx[j] = make_float2(bf2f((ushort_t)(pv & 0xffffu)), bf2f((ushort_t)(pv >> 16)));
  }
  __syncthreads();
  fft2048_r8<true>(bx, by, twg, tid);           // bx = Z (packed fwd FFT)
  const float2* afc = af + (long)c * 2052;
  for (int k = tid; k <= 1024; k += 256) {
    float2 Zk = bx[k], Zn = bx[(2048 - k) & 2047];
    float2 E = make_float2(0.5f * (Zk.x + Zn.x), 0.5f * (Zk.y - Zn.y));
    float2 O = make_float2(0.5f * (Zk.y + Zn.y), 0.5f * (Zn.x - Zk.x));
    float2 W = twh[k];
    float2 WO = cmulf(W, O);
    float2 Xk = make_float2(E.x + WO.x, E.y + WO.y);          // rfft(v)[k]
    float2 Xn = make_float2(E.x - WO.x, -(E.y - WO.y));       // rfft(v)[2048-k]
    float2 Pk = cmulf(Xk, afc[k]);
    float2 Pn = cmulf(Xn, afc[2048 - k]);
    // E2=(Pk+conj(Pn))/2, G=(Pk-conj(Pn))/2, Fo=conj(W)*G, W2=E2+i*Fo
    float2 E2 = make_float2(0.5f * (Pk.x + Pn.x), 0.5f * (Pk.y - Pn.y));
    float2 G  = make_float2(0.5f * (Pk.x - Pn.x), 0.5f * (Pk.y + Pn.y));
    float2 cW = make_float2(W.x, -W.y);
    float2 Fo = cmulf(cW, G);
    by[k] = make_float2(E2.x - Fo.y, -(E2.y + Fo.x));          // conj(W2[k])
    if (k != 0 && k != 1024) {
      const int kn = 2048 - k;
      by[kn] = make_float2(E2.x + Fo.y, E2.y - Fo.x);          // conj(W2[2048-k])
    }
  }
  __syncthreads();
  fft2048_r8<false>(by, bx, twg, tid);          // by = FFT(conj(W2))
  const float inv = 1.f / 2048.f;
#pragma unroll
  for (int jj = 0; jj < 4; ++jj) {              // z[j]=conj(by[j])/2048
    const int j = tid + jj * 256;
    float2 r = by[j];
    unsigned ov = (unsigned)f2bf(r.x * inv) | ((unsigned)f2bf(-r.y * inv) << 16);
    *(unsigned*)(vs + 2 * j) = ov;
  }
}

// gate IN PLACE: u[bn][c] *= conv[c][bn]   (conv lives in vt)
__launch_bounds__(256)
__global__ void gate_trans(const ushort_t* __restrict__ convt, ushort_t* __restrict__ u)
{
  __shared__ ushort_t tile[64][65];
  const int bc = (int)blockIdx.x % 24, br = (int)blockIdx.x / 24;
  const int c0 = bc << 6, r0 = br << 6;
  const int tx = threadIdx.x & 63, ty = threadIdx.x >> 6;
  for (int yy = ty; yy < 64; yy += 4)
    tile[yy][tx] = convt[(long)(c0 + yy) * 16384 + r0 + tx];
  __syncthreads();
  for (int yy = ty; yy < 64; yy += 4) {
    long ui = (long)(r0 + yy) * 1536 + c0 + tx;
    float uu = bf2f(u[ui]);
    float cc = bf2f(tile[tx][yy]);
    u[ui] = f2bf(uu * cc);
  }
}

// ===========================================================================
extern "C" void kernel_launch(void* const* d_in, const int* in_sizes, int n_in,
                              void* d_out, int out_size, void* d_ws, size_t ws_size,
                              hipStream_t stream)
{
  const float* x     = (const float*)d_in[0];
  const float* Wu    = (const float*)d_in[1];
  const float* bu    = (const float*)d_in[2];
  const float* Wv    = (const float*)d_in[3];
  const float* bv    = (const float*)d_in[4];
  const float* Wo    = (const float*)d_in[5];
  const float* bo    = (const float*)d_in[6];
  const float* rWin  = (const float*)d_in[7];
  const float* rbin  = (const float*)d_in[8];
  const float* rW    = (const float*)d_in[9];
  const float* rb    = (const float*)d_in[10];
  const float* rWout = (const float*)d_in[11];
  const float* rbout = (const float*)d_in[12];

  char* base = (char*)d_ws;
  size_t off = 0;
  auto alloc = [&](size_t bytes) -> char* {
    size_t r = (off + 255) & ~(size_t)255; off = r + bytes; return base + r;
  };
  ushort_t* wuvt   = (ushort_t*)alloc(3072L * 512 * 2);     // [Wu^T; Wv^T]  3MB
  ushort_t* wot    = (ushort_t*)alloc(512L * 1536 * 2);     // Wo^T        1.5MB
  ushort_t* wrt    = (ushort_t*)alloc(3L * 512 * 512 * 2);  // rpe_W^T x3  1.5MB
  ushort_t* wroutt = (ushort_t*)alloc(1536L * 512 * 2);     // rpe_Wout^T  1.5MB
  float*    buvb   = (float*)   alloc(3072L * 4);           // [bu;bv]
  ushort_t* a0     = (ushort_t*)alloc(2048L * 512 * 2);     // RPE act bf16  2MB
  float2*   af     = (float2*)  alloc(1536L * 2052 * 8);    // spectra    25.2MB
  float2*   twg    = (float2*)  alloc(2048L * 8);           // cis(-2pi j/2048)
  float2*   twh    = (float2*)  alloc(1025L * 8);           // cis(-pi k/2048)
  char*     X      = alloc(16384L * 512 * 2);               // xb | (h+kern) 16MB
  ushort_t* u      = (ushort_t*)alloc(16384L * 1536 * 2);   // u (later gated) 48MB
  ushort_t* vt     = (ushort_t*)alloc(1536L * 16384 * 2);   // v^T / conv^T  48MB
  ushort_t* xb   = (ushort_t*)X;
  float*    h    = (float*)X;
  float*    kern = (float*)(X + 4L * 1024 * 1024);

  const float lng = -0.01005033585350145f;   // ln(0.99)

  // ---- merged prep: weights, biases, x->bf16, twiddles, rpe_h0 ----
  prep_all<<<dim3(14094), dim3(256), 0, stream>>>(
      Wu, Wv, Wo, rW, rWout, bu, bv, x, rWin, rbin,
      wuvt, wot, wrt, wroutt, buvb, xb, twg, twh, a0);

  // ---- u/v projection (fused, v stored transposed) ----
  gemm_bt<3><<<dim3(3072), dim3(256), 0, stream>>>(xb, wuvt, buvb, u, vt,
                                                   16384, 3072, 512, 0.f);

  // ---- RPE chain -> kern[c][n] -> spectra af ----
  for (int i = 0; i < 3; ++i) {
    gemm_bt<0><<<dim3(64), dim3(256), 0, stream>>>(a0, wrt + (long)i * 512 * 512,
                                                   rb + (long)i * 512, h, nullptr,
                                                   2048, 512, 512, 0.f);
    rpe_norm<<<dim3(2048), dim3(256), 0, stream>>>(h, a0);
  }
  gemm_bt<2><<<dim3(192), dim3(256), 0, stream>>>(a0, wroutt, rbout, kern, nullptr,
                                                  2048, 1536, 512, lng);
  fft_kernel_spec<<<dim3(1536), dim3(256), 0, stream>>>(kern, af, twg, twh);

  // ---- FFT conv in place on vt, gate in place into u, out projection ----
  fft_conv<<<dim3(12288), dim3(256), 0, stream>>>(vt, af, twg, twh);
  gate_trans<<<dim3(6144), dim3(256), 0, stream>>>(vt, u);
  gemm_bt<0><<<dim3(512), dim3(256), 0, stream>>>(u, wot, bo, d_out, nullptr,
                                                  16384, 512, 1536, 0.f);
}